// Round 1
// baseline (74.255 us; speedup 1.0000x reference)
//
#include <hip/hip_runtime.h>

// GaussianAnsatzNN: out[k,d] = sum_m theta[m] * N * exp(-0.5*||x_k - mu_m||^2) * (mu_{m,d} - x_{k,d})
// Means form a separable 20^3 grid -> factorize the Gaussian into Ex_i*Ey_j*Ez_l
// and evaluate via tensor contractions.
//
// Round 1 restructure: occupancy attack.
//  - One i-plane per block (NCHUNK=20), KPB=64 (1 wave/block): grid 256x20 = 5120
//    blocks -> 20 waves/CU (was 640 blocks -> 10 waves/CU, 2.5/SIMD).
//  - Ey/Eyp computed on the fly in the j-loop (no 40-reg arrays) -> VGPR ~75.
//  - Stage only the 400-float theta row this block needs (LDS 32KB -> 1.8KB).

#define NG   20
#define KPB  64          // threads per block = k's per block (1 wave)

__global__ __launch_bounds__(KPB, 4) void gauss_factored_kernel(
    const float* __restrict__ x, const float* __restrict__ means,
    const float* __restrict__ theta, float* __restrict__ out) {
  __shared__ float sth[NG * NG];   // theta row for this block's i: theta[i*400 + j*20 + l]
  __shared__ float sgy[NG];        // grid values, y axis
  __shared__ float sgz[NG];        // grid values, z axis

  const int tid = threadIdx.x;
  const int i = blockIdx.y;        // this block's x-axis gaussian index

  // Stage this block's theta row (400 floats = 100 float4).
  {
    const float4* th4 = (const float4*)theta + i * (NG * NG / 4);
    float4* sth4 = (float4*)sth;
    for (int idx = tid; idx < NG * NG / 4; idx += KPB) sth4[idx] = th4[idx];
  }
  // Stage grid axis values: g_j = means[(j*20)*3+1], g_l = means[l*3+2]
  if (tid < 2 * NG) {
    const int axis = tid / NG, p = tid % NG;
    if (axis == 0) sgy[p] = means[p * 60 + 1];
    else           sgz[p] = means[p * 3 + 2];
  }
  // g_i for this block: means[(i*400)*3 + 0]; uniform -> broadcast load.
  const float gi = means[i * 1200];
  __syncthreads();

  const int k = blockIdx.x * KPB + tid;  // K = 16384 = 256*64, exact
  const float x0 = x[k * 3 + 0];
  const float x1 = x[k * 3 + 1];
  const float x2 = x[k * 3 + 2];

  // Per-thread z-axis factors (registers after full unroll): 40 VGPRs.
  float Ez[NG], Ezp[NG];
#pragma unroll
  for (int l = 0; l < NG; ++l) {
    const float dz = x2 - sgz[l];
    const float e = __expf(-0.5f * dz * dz);
    Ez[l] = e;
    Ezp[l] = -dz * e;  // Ez_l * (g_l - x2)
  }

  const float dxv = x0 - gi;
  const float ex = __expf(-0.5f * dxv * dxv);
  const float exn = -dxv * ex;  // Ex_i * (g_i - x0)

  float b = 0.f, b1 = 0.f, b2 = 0.f;
#pragma unroll
  for (int j = 0; j < NG; ++j) {
    const float dy = x1 - sgy[j];
    const float ey = __expf(-0.5f * dy * dy);

    const float4* trow = (const float4*)(sth + j * NG);  // 16B-aligned, wave-uniform -> broadcast
    float aZ0 = 0.f, aZ1 = 0.f, aZp0 = 0.f, aZp1 = 0.f;
#pragma unroll
    for (int l4 = 0; l4 < 5; ++l4) {
      const float4 t = trow[l4];
      aZ0  = fmaf(t.x, Ez [4 * l4 + 0], aZ0);
      aZp0 = fmaf(t.x, Ezp[4 * l4 + 0], aZp0);
      aZ1  = fmaf(t.y, Ez [4 * l4 + 1], aZ1);
      aZp1 = fmaf(t.y, Ezp[4 * l4 + 1], aZp1);
      aZ0  = fmaf(t.z, Ez [4 * l4 + 2], aZ0);
      aZp0 = fmaf(t.z, Ezp[4 * l4 + 2], aZp0);
      aZ1  = fmaf(t.w, Ez [4 * l4 + 3], aZ1);
      aZp1 = fmaf(t.w, Ezp[4 * l4 + 3], aZp1);
    }
    const float aZ = aZ0 + aZ1;
    const float aZp = aZp0 + aZp1;
    const float eyAZ = ey * aZ;
    b += eyAZ;                   // sum_j Ey_j * aZ
    b1 = fmaf(-dy, eyAZ, b1);    // sum_j Eyp_j * aZ  (Eyp = -dy*Ey)
    b2 = fmaf(ey, aZp, b2);      // sum_j Ey_j * aZp
  }

  const float Nc = 0.06349363593424097f;  // (2*pi)^{-3/2}
  atomicAdd(&out[k * 3 + 0], exn * b * Nc);
  atomicAdd(&out[k * 3 + 1], ex * b1 * Nc);
  atomicAdd(&out[k * 3 + 2], ex * b2 * Nc);
}

extern "C" void kernel_launch(void* const* d_in, const int* in_sizes, int n_in,
                              void* d_out, int out_size, void* d_ws, size_t ws_size,
                              hipStream_t stream) {
  const float* x = (const float*)d_in[0];      // (K, 3)
  const float* means = (const float*)d_in[1];  // (8000, 3)
  const float* theta = (const float*)d_in[2];  // (8000,)
  float* out = (float*)d_out;                  // (K, 3)

  const int K = in_sizes[0] / 3;

  // d_out is re-poisoned before every call; zero it (memset node is graph-capturable).
  hipMemsetAsync(out, 0, (size_t)out_size * sizeof(float), stream);

  dim3 grid(K / KPB, NG);
  gauss_factored_kernel<<<grid, KPB, 0, stream>>>(x, means, theta, out);
}